// Round 4
// baseline (1398.626 us; speedup 1.0000x reference)
//
#include <hip/hip_runtime.h>

// MaxUnpooling2D scatter-add — round 8: single fused persistent kernel.
//
// R7 post-mortem: R6->R7 within noise (1109 vs 1133). Three rounds blind:
// all our kernels < 336 us, so harness 2-GiB fills own the top-5 and we
// get no per-stage counters. Pipeline ideal ~230 us vs ~600+ observed:
// hypothesis = LDS-atomic-issue-bound stages (33.5M ds_atomic_add per
// stage = 131K/CU) that can't hide under each stage's small BW time,
// plus 5 inter-dispatch boundaries.
//
// R8: fuse everything into ONE kernel, 256 blocks x 1024 thr, 133 KB LDS
// -> exactly 1 block/CU x 256 CUs, all-resident -> manual device-scope
// atomic grid barrier is safe (standard cooperative grid.sync pattern).
//   - 4 grid barriers: hist | colsum | scan | place || apply.
//   - block's hist stays in LDS across phases; per-block offsets rebuilt
//     locally (bbase + column prefix) -> p2_expand pass deleted.
//   - apply phase: block handles windows h = i*256 + blk, i = 0..15;
//     h >= 1408 are pure zero-streams (tail), windows first then tails.
//   - diagnostic win: the fused dispatch (~400-550 us) finally lands in
//     the top-5 with real FETCH/WRITE/LDS-conflict counters.
// Pre-commits: WRITE >= 1.2 GB -> CB=15 amp broke, revert window scheme;
// deadlock/timeout -> revert to R6 separate kernels.

typedef float floatx4 __attribute__((ext_vector_type(4)));
typedef int   intx4   __attribute__((ext_vector_type(4)));

constexpr int FLAT_IN   = 1 << 22;                 // 4,194,304
constexpr int N_ELEMS   = 8 * FLAT_IN;             // 33,554,432
constexpr int OUT_WIN   = 7 * FLAT_IN + (1 << 24); // 46,137,344
constexpr int OUT_TOTAL = 134217728;

constexpr int CB_SHIFT = 15;                    // bucket = window = 32K floats = 128 KB
constexpr int APW      = 1 << CB_SHIFT;         // 32768
constexpr int NBC      = OUT_WIN >> CB_SHIFT;   // 1408 buckets with data
constexpr int NBC_PAD  = 1536;                  // padded (6*256) for scan
constexpr int WIN_B    = 512;                   // buckets per block's 2^24 input window
constexpr int NAP      = OUT_TOTAL >> CB_SHIFT; // 4096 output windows incl. tail

constexpr int GRID     = 256;                   // == #CUs; all-resident (1 blk/CU via LDS)
constexpr int TPB      = 1024;
constexpr int CHUNK    = N_ELEMS / GRID;        // 131072
constexpr int ITERS    = CHUNK / (4 * TPB);     // 32

// ---- workspace layout (bytes) ----
constexpr size_t WS_PAIRS  = 0;                                      // int2[N_ELEMS] = 268,435,456
constexpr size_t WS_HIST   = 268435456;                              // int[GRID][NBC_PAD] = 1,572,864
constexpr size_t WS_TOT    = WS_HIST + (size_t)GRID * NBC_PAD * 4;   // int[NBC_PAD]
constexpr size_t WS_BBASE  = WS_TOT + (size_t)NBC_PAD * 4;           // int[NBC_PAD+1] (+pad)
constexpr size_t WS_BAR    = WS_BBASE + (size_t)(NBC_PAD + 16) * 4;  // int[4], 16B aligned
constexpr size_t WS_NEEDED = WS_BAR + 64;

// ---------------- K0: zero a float4 range (nontemporal) ----------------
__global__ __launch_bounds__(256) void zero_kernel(floatx4* __restrict__ p, int n4) {
  int i = blockIdx.x * 256 + threadIdx.x;
  int stride = gridDim.x * 256;
  floatx4 z = {0.f, 0.f, 0.f, 0.f};
  for (; i < n4; i += stride) __builtin_nontemporal_store(z, p + i);
}

// ---------------- device-scope grid barrier (all blocks resident) ----------------
__device__ __forceinline__ void grid_sync(int* bar, int target) {
  __syncthreads();
  if (threadIdx.x == 0) {
    __threadfence();  // release all prior global writes (device scope)
    __hip_atomic_fetch_add(bar, 1, __ATOMIC_ACQ_REL, __HIP_MEMORY_SCOPE_AGENT);
    while (__hip_atomic_load(bar, __ATOMIC_ACQUIRE, __HIP_MEMORY_SCOPE_AGENT) < target)
      __builtin_amdgcn_s_sleep(2);
  }
  __syncthreads();
}

// ---------------- the fused pipeline ----------------
__global__ __launch_bounds__(TPB) void mega(const intx4* __restrict__ mask4,
                                            const floatx4* __restrict__ upd4,
                                            int* __restrict__ hist,
                                            int* __restrict__ tot,
                                            int* __restrict__ bbase,
                                            int* __restrict__ bar,
                                            int2* __restrict__ pairs,
                                            float* __restrict__ out) {
  __shared__ float win[APW];       // 128 KB
  __shared__ int   cnt[WIN_B];     // 2 KB
  __shared__ int   rowbase[WIN_B]; // 2 KB
  __shared__ int   partial[256];   // 1 KB (scan scratch)

  const int blk = blockIdx.x, tid = threadIdx.x;
  const int base4 = blk * (CHUNK / 4);
  const int boff  = (blk * CHUNK) & ~(FLAT_IN - 1);  // block-uniform batch offset
  const int cb0   = boff >> CB_SHIFT;                // multiple of 128

  // ===== phase 1: histogram of this block's chunk (cnt stays in LDS) =====
  for (int j = tid; j < WIN_B; j += TPB) cnt[j] = 0;
  __syncthreads();
  #pragma unroll 4
  for (int k = 0; k < ITERS; ++k) {
    intx4 m = mask4[base4 + k * TPB + tid];  // regular loads: L3-retained for phase 3
    atomicAdd(&cnt[m.x >> CB_SHIFT], 1);     // m.* < 2^24 -> idx < 512
    atomicAdd(&cnt[m.y >> CB_SHIFT], 1);
    atomicAdd(&cnt[m.z >> CB_SHIFT], 1);
    atomicAdd(&cnt[m.w >> CB_SHIFT], 1);
  }
  __syncthreads();
  for (int j = tid; j < NBC_PAD; j += TPB) {
    int jj = j - cb0;
    hist[(size_t)blk * NBC_PAD + j] = (jj >= 0 && jj < WIN_B) ? cnt[jj] : 0;
  }
  grid_sync(bar, 1 * GRID);

  // ===== phase 2a: column totals (6 columns per block) =====
  if (tid < 6) {
    int j = blk * 6 + tid;
    int s = 0;
    for (int r = 0; r < GRID; ++r) s += hist[(size_t)r * NBC_PAD + j];
    tot[j] = s;
  }
  grid_sync(bar, 2 * GRID);

  // ===== phase 2b: exclusive scan of tot -> bbase (block 0 only) =====
  if (blk == 0) {
    int local = 0;
    if (tid < 256) {
      #pragma unroll
      for (int k = 0; k < NBC_PAD / 256; ++k) local += tot[tid * (NBC_PAD / 256) + k];
      partial[tid] = local;
    }
    __syncthreads();
    for (int off = 1; off < 256; off <<= 1) {
      int tmp = (tid < 256 && tid >= off) ? partial[tid - off] : 0;
      __syncthreads();
      if (tid < 256) partial[tid] += tmp;
      __syncthreads();
    }
    if (tid < 256) {
      int run = partial[tid] - local;
      #pragma unroll
      for (int k = 0; k < NBC_PAD / 256; ++k) {
        int b = tid * (NBC_PAD / 256) + k;
        bbase[b] = run;
        run += tot[b];
      }
      if (tid == 255) bbase[NBC_PAD] = run;  // == N_ELEMS
    }
  }
  grid_sync(bar, 3 * GRID);

  // ===== phase 2c (block-local): rowbase = bbase + prefix of preceding rows =====
  for (int j = tid; j < WIN_B; j += TPB) {
    int g = cb0 + j;
    int run = bbase[g];
    for (int r = 0; r < blk; ++r) run += hist[(size_t)r * NBC_PAD + g];
    rowbase[j] = run;
    cnt[j] = 0;  // reset for arrival ranks
  }
  __syncthreads();

  // ===== phase 3: place pairs (NT streaming loads) =====
  #pragma unroll 2
  for (int k = 0; k < ITERS; ++k) {
    int j4 = base4 + k * TPB + tid;
    intx4 m = __builtin_nontemporal_load(mask4 + j4);
    floatx4 u = __builtin_nontemporal_load(upd4 + j4);
    {
      int b = m.x >> CB_SHIFT; int r = atomicAdd(&cnt[b], 1);
      pairs[rowbase[b] + r] = make_int2(m.x + boff, __float_as_int(u.x));
    }
    {
      int b = m.y >> CB_SHIFT; int r = atomicAdd(&cnt[b], 1);
      pairs[rowbase[b] + r] = make_int2(m.y + boff, __float_as_int(u.y));
    }
    {
      int b = m.z >> CB_SHIFT; int r = atomicAdd(&cnt[b], 1);
      pairs[rowbase[b] + r] = make_int2(m.z + boff, __float_as_int(u.z));
    }
    {
      int b = m.w >> CB_SHIFT; int r = atomicAdd(&cnt[b], 1);
      pairs[rowbase[b] + r] = make_int2(m.w + boff, __float_as_int(u.w));
    }
  }
  grid_sync(bar, 4 * GRID);

  // ===== phase 4: apply — block handles windows h = i*256 + blk =====
  floatx4* w4 = (floatx4*)win;
  floatx4 z = {0.f, 0.f, 0.f, 0.f};
  #pragma unroll 1
  for (int i = 0; i < NAP / GRID; ++i) {  // 16; windows first, then tails (monotone)
    const int h = i * GRID + blk;
    floatx4* o4 = (floatx4*)(out + (size_t)h * APW);
    if (h >= NBC) {
      // tail window: pure zero stream, no LDS involved
      #pragma unroll
      for (int k = 0; k < APW / 4 / TPB; ++k)
        __builtin_nontemporal_store(z, o4 + k * TPB + tid);
    } else {
      __syncthreads();  // previous window's stores fully read
      #pragma unroll
      for (int k = 0; k < APW / 4 / TPB; ++k) w4[k * TPB + tid] = z;
      __syncthreads();
      const int s = bbase[h], e = bbase[h + 1];
      const int s4 = (s + 1) & ~1;  // first even pair index (16B-aligned)
      if ((s & 1) && s < e && tid == 0) {
        int2 p = pairs[s];
        atomicAdd(&win[p.x & (APW - 1)], __int_as_float(p.y));
      }
      const int n2 = (e > s4) ? ((e - s4) >> 1) : 0;
      const intx4* pv = (const intx4*)(pairs + s4);
      for (int i2 = tid; i2 < n2; i2 += TPB) {
        intx4 q = __builtin_nontemporal_load(pv + i2);
        atomicAdd(&win[q.x & (APW - 1)], __int_as_float(q.y));
        atomicAdd(&win[q.z & (APW - 1)], __int_as_float(q.w));
      }
      if ((e > s4) && ((e - s4) & 1) && tid == 0) {
        int2 p = pairs[e - 1];
        atomicAdd(&win[p.x & (APW - 1)], __int_as_float(p.y));
      }
      __syncthreads();
      #pragma unroll
      for (int k = 0; k < APW / 4 / TPB; ++k)
        __builtin_nontemporal_store(w4[k * TPB + tid], o4 + k * TPB + tid);
    }
  }
}

// ---------------- fallback: R1 atomic scatter ----------------
__global__ __launch_bounds__(256) void scatter_add4_kernel(
    const float4* __restrict__ upd4, const int4* __restrict__ msk4,
    float* __restrict__ out, int n4) {
  int j = blockIdx.x * blockDim.x + threadIdx.x;
  if (j >= n4) return;
  float4 u = upd4[j];
  int4 m = msk4[j];
  int base = (j * 4) & ~(FLAT_IN - 1);
  unsafeAtomicAdd(out + (base + m.x), u.x);
  unsafeAtomicAdd(out + (base + m.y), u.y);
  unsafeAtomicAdd(out + (base + m.z), u.z);
  unsafeAtomicAdd(out + (base + m.w), u.w);
}

extern "C" void kernel_launch(void* const* d_in, const int* in_sizes, int n_in,
                              void* d_out, int out_size, void* d_ws, size_t ws_size,
                              hipStream_t stream) {
  const float* updates = (const float*)d_in[0];
  const int*   mask    = (const int*)d_in[1];
  float*       out     = (float*)d_out;
  const int n = in_sizes[0];

  const bool fast = (n == N_ELEMS) && (out_size == OUT_TOTAL) && (ws_size >= WS_NEEDED);

  if (!fast) {
    int n4z = out_size / 4;
    zero_kernel<<<(n4z + 2047) / 2048, 256, 0, stream>>>((floatx4*)d_out, n4z);
    int n4 = n / 4;
    scatter_add4_kernel<<<(n4 + 255) / 256, 256, 0, stream>>>(
        (const float4*)updates, (const int4*)mask, out, n4);
    return;
  }

  char* ws = (char*)d_ws;
  int2* pairs = (int2*)(ws + WS_PAIRS);
  int*  hist  = (int*)(ws + WS_HIST);
  int*  tot   = (int*)(ws + WS_TOT);
  int*  bbase = (int*)(ws + WS_BBASE);
  int*  bar   = (int*)(ws + WS_BAR);

  // barrier counter starts poisoned every iteration -> zero it first
  zero_kernel<<<1, 256, 0, stream>>>((floatx4*)bar, 1);
  mega<<<GRID, TPB, 0, stream>>>((const intx4*)mask, (const floatx4*)updates,
                                 hist, tot, bbase, bar, pairs, out);
}